// Round 1
// baseline (426.711 us; speedup 1.0000x reference)
//
#include <hip/hip_runtime.h>
#include <cstdint>
#include <cstddef>

// Problem constants
#define BB 2
#define FF 16
#define NPT 128
#define CC 1280
#define MID 128
// base grid 32x32 per (b,f) image; BF = 32 images; 32768 cells total

// ---------------------------------------------------------------------------
// K1: pe1[b,n,l,m] = sum_c pe[b,n,c] * w1s[l,c,m]   (256 rows x 512 cols, K=1280)
// 4 pe-rows per block staged in LDS; w1 column read once per 4 rows.
__global__ __launch_bounds__(256) void k_pe1(const float* __restrict__ pe,
                                             const float* __restrict__ w1s,
                                             float* __restrict__ pe1) {
  int bn0 = blockIdx.x * 4;  // 64 blocks cover 256 (b,n) rows
  __shared__ float rows[4][CC];
  for (int i = threadIdx.x; i < 4 * CC; i += 256) {
    rows[i / CC][i % CC] = pe[(size_t)bn0 * CC + i];
  }
  __syncthreads();
  for (int o = threadIdx.x; o < 512; o += 256) {  // o = l*128 + m
    int l = o >> 7, m = o & 127;
    const float* w = w1s + (size_t)l * CC * MID + m;
    float a0 = 0.f, a1 = 0.f, a2 = 0.f, a3 = 0.f;
#pragma unroll 4
    for (int c = 0; c < CC; ++c) {
      float wv = w[(size_t)c * MID];
      a0 = fmaf(rows[0][c], wv, a0);
      a1 = fmaf(rows[1][c], wv, a1);
      a2 = fmaf(rows[2][c], wv, a2);
      a3 = fmaf(rows[3][c], wv, a3);
    }
    pe1[(size_t)(bn0 + 0) * 512 + o] = a0;
    pe1[(size_t)(bn0 + 1) * 512 + o] = a1;
    pe1[(size_t)(bn0 + 2) * 512 + o] = a2;
    pe1[(size_t)(bn0 + 3) * 512 + o] = a3;
  }
}

// ---------------------------------------------------------------------------
// K2: per-image counting sort of points into cells. counts = full hit count,
// plist holds up to 32 point indices per cell (P(overflow) ~ 0 for this data).
__global__ __launch_bounds__(128) void k_bin(const float* __restrict__ kp,
                                             const int* __restrict__ subsets,
                                             int* __restrict__ counts,
                                             int* __restrict__ plist) {
  int bf = blockIdx.x;  // 0..31
  __shared__ int lcnt[1024];
  for (int i = threadIdx.x; i < 1024; i += 128) lcnt[i] = 0;
  __syncthreads();
  int n = threadIdx.x;
  int p = bf * NPT + n;
  float kx = kp[2 * p], ky = kp[2 * p + 1];
  int sub = subsets[p];
  if (fminf(kx, ky) >= 0.f && sub != -1) {
    int px = (int)floorf(kx * 32.f);
    px = px < 0 ? 0 : (px > 31 ? 31 : px);
    int py = (int)floorf(ky * 32.f);
    py = py < 0 ? 0 : (py > 31 ? 31 : py);
    int cell = py * 32 + px;
    int slot = atomicAdd(&lcnt[cell], 1);
    if (slot < 32) plist[((size_t)bf * 1024 + cell) * 32 + slot] = n;
  }
  __syncthreads();
  for (int i = threadIdx.x; i < 1024; i += 128) counts[bf * 1024 + i] = lcnt[i];
}

// ---------------------------------------------------------------------------
// K3: for NON-EMPTY cells only: hidm[cell][l*128+m] = silu(mean(pe1 rows) + b1)
// Empty cells left as garbage; consumers gate on counts>0 with selects.
__global__ __launch_bounds__(256) void k_hid(const float* __restrict__ pe1,
                                             const int* __restrict__ counts,
                                             const int* __restrict__ plist,
                                             const float* __restrict__ b1s,
                                             float* __restrict__ hidm) {
  int cell = blockIdx.x;  // 0..32767
  int c = counts[cell];
  if (c == 0) return;
  int cu = c < 32 ? c : 32;
  int b = cell >> 14;  // 16384 cells per batch item
  __shared__ int lst[32];
  if ((int)threadIdx.x < cu) lst[threadIdx.x] = plist[(size_t)cell * 32 + threadIdx.x];
  __syncthreads();
  float invc = 1.f / (float)c;
  for (int j = threadIdx.x; j < 512; j += 256) {
    float sum = 0.f;
    for (int i = 0; i < cu; ++i) sum += pe1[(size_t)(b * NPT + lst[i]) * 512 + j];
    float t = sum * invc + b1s[j];
    hidm[(size_t)cell * 512 + j] = t / (1.f + expf(-t));
  }
}

// ---------------------------------------------------------------------------
// K4: per-level GEMM with fused downsample + mask.
// out[img,k,y,x] = Mn(y,x) * ( g(y,x,:) @ w2[:,k] + Ss(y,x)*b2[k] )
//   level 0: g = mask*hid (scale 1); levels 1-3: g = 0.25*sum of 2x2 block of mask*hid.
// 64 spatial x 64 channel tile, K=128, XOR-swizzled LDS, float4 reads.
template <int SCALE, int OFF, int AGG, int LOGW>
__global__ __launch_bounds__(256) void k_gemm(const float* __restrict__ hidm,
                                              const int* __restrict__ counts,
                                              const float* __restrict__ w2,
                                              const float* __restrict__ b2,
                                              float* __restrict__ out,
                                              int lvl, int ch) {
  const int WRES = 1 << LOGW;
  const int SDIM = WRES * WRES;
  __shared__ __align__(16) float As[64 * 128];
  __shared__ __align__(16) float Ws[64 * 128];
  __shared__ float Ss[64], Mn[64];
  int img = blockIdx.z;
  int k0 = blockIdx.y * 64;
  int s0 = blockIdx.x * 64;
  const int cbase = img * 1024;

  // stage W^T: Ws[k][m] = w2[m*ch + k0+k], XOR-swizzled on m-groups
  for (int idx = threadIdx.x; idx < 64 * MID; idx += 256) {
    int k = idx & 63, m = idx >> 6;
    Ws[k * 128 + (m ^ ((k & 7) << 2))] = w2[(size_t)m * ch + k0 + k];
  }
  // stage A (aggregated, masked)
  for (int idx = threadIdx.x; idx < 64 * MID; idx += 256) {
    int s = idx >> 7, m = idx & 127;
    int sp = s0 + s;
    int y = sp >> LOGW, x = sp & (WRES - 1);
    float g;
    if (AGG) {
      int ay = SCALE * y + OFF, ax = SCALE * x + OFF;
      int c00 = cbase + ay * 32 + ax;
      float v = 0.f;
      int cc;
      cc = counts[c00];      v += (cc > 0) ? hidm[(size_t)c00 * 512 + lvl * 128 + m] : 0.f;
      cc = counts[c00 + 1];  v += (cc > 0) ? hidm[(size_t)(c00 + 1) * 512 + lvl * 128 + m] : 0.f;
      cc = counts[c00 + 32]; v += (cc > 0) ? hidm[(size_t)(c00 + 32) * 512 + lvl * 128 + m] : 0.f;
      cc = counts[c00 + 33]; v += (cc > 0) ? hidm[(size_t)(c00 + 33) * 512 + lvl * 128 + m] : 0.f;
      g = 0.25f * v;
    } else {
      int cell = cbase + sp;
      g = (counts[cell] > 0) ? hidm[(size_t)cell * 512 + lvl * 128 + m] : 0.f;
    }
    As[s * 128 + (m ^ ((s & 7) << 2))] = g;
  }
  // per-spatial mask terms
  if (threadIdx.x < 64) {
    int s = threadIdx.x;
    int sp = s0 + s;
    int y = sp >> LOGW, x = sp & (WRES - 1);
    if (AGG) {
      int ay = SCALE * y + OFF, ax = SCALE * x + OFF;
      int c00 = cbase + ay * 32 + ax;
      float m00 = counts[c00] > 0 ? 1.f : 0.f;
      float m01 = counts[c00 + 1] > 0 ? 1.f : 0.f;
      float m10 = counts[c00 + 32] > 0 ? 1.f : 0.f;
      float m11 = counts[c00 + 33] > 0 ? 1.f : 0.f;
      Ss[s] = 0.25f * (m00 + m01 + m10 + m11);
      Mn[s] = counts[cbase + (SCALE * y) * 32 + SCALE * x] > 0 ? 1.f : 0.f;
    } else {
      float mv = counts[cbase + sp] > 0 ? 1.f : 0.f;
      Ss[s] = mv;
      Mn[s] = mv;
    }
  }
  __syncthreads();

  int ts = threadIdx.x & 15;  // spatial lane (s = ts + 16*i) -> coalesced stores
  int tk = threadIdx.x >> 4;  // channel lane (k = tk + 16*j)
  float acc[4][4] = {};       // [j: k][i: s]
  for (int mb = 0; mb < 32; ++mb) {
    int m4 = mb << 2;
    float4 a[4], w[4];
#pragma unroll
    for (int i = 0; i < 4; ++i) {
      int r = ts + 16 * i;
      a[i] = *reinterpret_cast<const float4*>(&As[r * 128 + (m4 ^ ((r & 7) << 2))]);
    }
#pragma unroll
    for (int j = 0; j < 4; ++j) {
      int r = tk + 16 * j;
      w[j] = *reinterpret_cast<const float4*>(&Ws[r * 128 + (m4 ^ ((r & 7) << 2))]);
    }
#pragma unroll
    for (int j = 0; j < 4; ++j) {
#pragma unroll
      for (int i = 0; i < 4; ++i) {
        float t = acc[j][i];
        t = fmaf(a[i].x, w[j].x, t);
        t = fmaf(a[i].y, w[j].y, t);
        t = fmaf(a[i].z, w[j].z, t);
        t = fmaf(a[i].w, w[j].w, t);
        acc[j][i] = t;
      }
    }
  }
  // epilogue
#pragma unroll
  for (int j = 0; j < 4; ++j) {
    int k = k0 + tk + 16 * j;
    float bv = b2[k];
    float* op = out + ((size_t)img * ch + k) * SDIM + s0;
#pragma unroll
    for (int i = 0; i < 4; ++i) {
      int s = ts + 16 * i;
      op[s] = Mn[s] * (acc[j][i] + Ss[s] * bv);
    }
  }
}

// ---------------------------------------------------------------------------
__global__ __launch_bounds__(256) void k_ones(float* __restrict__ p, int n) {
  int i = blockIdx.x * 256 + threadIdx.x;
  if (i < n) p[i] = 1.f;
}

// ---------------------------------------------------------------------------
extern "C" void kernel_launch(void* const* d_in, const int* in_sizes, int n_in,
                              void* d_out, int out_size, void* d_ws, size_t ws_size,
                              hipStream_t stream) {
  const float* pe = (const float*)d_in[0];
  const float* kp = (const float*)d_in[1];
  const int* subsets = (const int*)d_in[2];
  // d_in[3] = pose_latents (unused by the reference)
  const float* w1s = (const float*)d_in[4];
  const float* b1s = (const float*)d_in[5];
  const float* w2l[4] = {(const float*)d_in[6], (const float*)d_in[8],
                         (const float*)d_in[10], (const float*)d_in[12]};
  const float* b2l[4] = {(const float*)d_in[7], (const float*)d_in[9],
                         (const float*)d_in[11], (const float*)d_in[13]};
  float* out = (float*)d_out;

  // workspace layout (4-byte units)
  float* pe1 = (float*)d_ws;             // 131072 floats
  int* counts = (int*)(pe1 + 131072);    // 32768 ints
  int* plist = counts + 32768;           // 32768*32 ints
  float* hidm = (float*)(plist + 32768 * 32);  // 32768*512 floats

  k_pe1<<<dim3(64), dim3(256), 0, stream>>>(pe, w1s, pe1);
  k_bin<<<dim3(32), dim3(128), 0, stream>>>(kp, subsets, counts, plist);
  k_hid<<<dim3(32768), dim3(256), 0, stream>>>(pe1, counts, plist, b1s, hidm);

  float* out0 = out;                  // (2,16,320,32,32)  = 10485760
  float* out1 = out + 10485760;       // (2,16,640,16,16)  =  5242880
  float* out2 = out + 15728640;       // (2,16,1280,8,8)   =  2621440
  float* out3 = out + 18350080;       // (2,16,1280,8,8)   =  2621440
  float* lossm = out + 20971520;      // (2,16,4,32,32)    =   131072

  k_gemm<1, 0, 0, 5><<<dim3(16, 5, 32), dim3(256), 0, stream>>>(hidm, counts, w2l[0], b2l[0], out0, 0, 320);
  k_gemm<2, 0, 1, 4><<<dim3(4, 10, 32), dim3(256), 0, stream>>>(hidm, counts, w2l[1], b2l[1], out1, 1, 640);
  k_gemm<4, 1, 1, 3><<<dim3(1, 20, 32), dim3(256), 0, stream>>>(hidm, counts, w2l[2], b2l[2], out2, 2, 1280);
  k_gemm<4, 1, 1, 3><<<dim3(1, 20, 32), dim3(256), 0, stream>>>(hidm, counts, w2l[3], b2l[3], out3, 3, 1280);

  k_ones<<<dim3(512), dim3(256), 0, stream>>>(lossm, 131072);
}

// Round 2
// 284.876 us; speedup vs baseline: 1.4979x; 1.4979x over previous
//
#include <hip/hip_runtime.h>
#include <cstdint>
#include <cstddef>

// Problem constants
#define BB 2
#define FF 16
#define NPT 128
#define CC 1280
#define MID 128
// base grid 32x32 per (b,f) image; BF = 32 images; 32768 cells total

// ---------------------------------------------------------------------------
// K1a: split-K partial GEMM  pe(256x1280) @ w1s(1280x512) -> part[z][256][512]
// grid (8 ntiles, 4 mtiles, 16 ksplits) = 512 blocks, 256 threads.
// 64x64 tile, K-chunk 80. LDS ~42KB.
__global__ __launch_bounds__(256) void k_pe1p(const float* __restrict__ pe,
                                              const float* __restrict__ w1s,
                                              float* __restrict__ part) {
  const int KC = 80;
  __shared__ __align__(16) float As[64 * 84];   // padded row stride 84
  __shared__ __align__(16) float Bs[KC * 64];
  int n0 = blockIdx.x * 64;
  int m0 = blockIdx.y * 64;
  int kc0 = blockIdx.z * KC;
  int tid = threadIdx.x;
  // stage A: 64 rows x 80 k
  for (int idx = tid; idx < 64 * 20; idx += 256) {
    int row = idx / 20, kk = idx % 20;
    float4 v = *reinterpret_cast<const float4*>(&pe[(size_t)(m0 + row) * CC + kc0 + kk * 4]);
    *reinterpret_cast<float4*>(&As[row * 84 + kk * 4]) = v;
  }
  // stage B: 80 k x 64 cols (cols live within one level slice of w1s)
  int l = n0 >> 7, m0c = n0 & 127;
  const float* wbase = w1s + (size_t)l * CC * MID + m0c;
  for (int idx = tid; idx < KC * 16; idx += 256) {
    int k = idx / 16, cg = idx % 16;
    float4 v = *reinterpret_cast<const float4*>(&wbase[(size_t)(kc0 + k) * MID + cg * 4]);
    *reinterpret_cast<float4*>(&Bs[k * 64 + cg * 4]) = v;
  }
  __syncthreads();
  int tx = tid & 15, ty = tid >> 4;
  float acc[4][4] = {};
  for (int k4 = 0; k4 < KC; k4 += 4) {
    float4 a[4], b[4];
#pragma unroll
    for (int i = 0; i < 4; ++i)
      a[i] = *reinterpret_cast<const float4*>(&As[(ty * 4 + i) * 84 + k4]);
#pragma unroll
    for (int kk = 0; kk < 4; ++kk)
      b[kk] = *reinterpret_cast<const float4*>(&Bs[(k4 + kk) * 64 + tx * 4]);
#pragma unroll
    for (int i = 0; i < 4; ++i) {
      float av[4] = {a[i].x, a[i].y, a[i].z, a[i].w};
#pragma unroll
      for (int kk = 0; kk < 4; ++kk) {
        acc[i][0] = fmaf(av[kk], b[kk].x, acc[i][0]);
        acc[i][1] = fmaf(av[kk], b[kk].y, acc[i][1]);
        acc[i][2] = fmaf(av[kk], b[kk].z, acc[i][2]);
        acc[i][3] = fmaf(av[kk], b[kk].w, acc[i][3]);
      }
    }
  }
  float* pb = part + (size_t)blockIdx.z * 131072;
#pragma unroll
  for (int i = 0; i < 4; ++i) {
    float4 v = make_float4(acc[i][0], acc[i][1], acc[i][2], acc[i][3]);
    *reinterpret_cast<float4*>(&pb[(size_t)(m0 + ty * 4 + i) * 512 + n0 + tx * 4]) = v;
  }
}

// K1b: pe1 = sum of 16 partials
__global__ __launch_bounds__(256) void k_red(const float* __restrict__ part,
                                             float* __restrict__ pe1) {
  int i = blockIdx.x * 256 + threadIdx.x;  // 0..32767 float4 groups
  float4 s = make_float4(0.f, 0.f, 0.f, 0.f);
#pragma unroll
  for (int z = 0; z < 16; ++z) {
    float4 v = *reinterpret_cast<const float4*>(&part[(size_t)z * 131072 + (size_t)i * 4]);
    s.x += v.x; s.y += v.y; s.z += v.z; s.w += v.w;
  }
  *reinterpret_cast<float4*>(&pe1[(size_t)i * 4]) = s;
}

// ---------------------------------------------------------------------------
// K2: per-image counting sort of points into cells + compact non-empty worklist.
__global__ __launch_bounds__(128) void k_bin(const float* __restrict__ kp,
                                             const int* __restrict__ subsets,
                                             int* __restrict__ counts,
                                             int* __restrict__ plist,
                                             int* __restrict__ wcnt,
                                             int* __restrict__ wlist) {
  int bf = blockIdx.x;  // 0..31
  __shared__ int lcnt[1024];
  for (int i = threadIdx.x; i < 1024; i += 128) lcnt[i] = 0;
  __syncthreads();
  int n = threadIdx.x;
  int p = bf * NPT + n;
  float kx = kp[2 * p], ky = kp[2 * p + 1];
  int sub = subsets[p];
  if (fminf(kx, ky) >= 0.f && sub != -1) {
    int px = (int)floorf(kx * 32.f);
    px = px < 0 ? 0 : (px > 31 ? 31 : px);
    int py = (int)floorf(ky * 32.f);
    py = py < 0 ? 0 : (py > 31 ? 31 : py);
    int cell = py * 32 + px;
    int slot = atomicAdd(&lcnt[cell], 1);
    if (slot < 32) plist[((size_t)bf * 1024 + cell) * 32 + slot] = n;
  }
  __syncthreads();
  for (int i = threadIdx.x; i < 1024; i += 128) {
    int c = lcnt[i];
    counts[bf * 1024 + i] = c;
    if (c > 0) {
      int pos = atomicAdd(wcnt, 1);
      wlist[pos] = bf * 1024 + i;
    }
  }
}

// ---------------------------------------------------------------------------
// K3: worklist-driven: hidm[cell][l*128+m] = silu(mean(pe1 rows) + b1)
__global__ __launch_bounds__(256) void k_hid(const float* __restrict__ pe1,
                                             const int* __restrict__ counts,
                                             const int* __restrict__ plist,
                                             const int* __restrict__ wcnt,
                                             const int* __restrict__ wlist,
                                             const float* __restrict__ b1s,
                                             float* __restrict__ hidm) {
  __shared__ int lst[32];
  int total = *wcnt;
  for (int w = blockIdx.x; w < total; w += 1024) {
    int cell = wlist[w];
    int c = counts[cell];
    int cu = c < 32 ? c : 32;
    int b = cell >> 14;  // 16384 cells per batch item
    __syncthreads();
    if ((int)threadIdx.x < cu) lst[threadIdx.x] = plist[(size_t)cell * 32 + threadIdx.x];
    __syncthreads();
    float invc = 1.f / (float)c;
    for (int j = threadIdx.x; j < 512; j += 256) {
      float sum = 0.f;
      for (int i = 0; i < cu; ++i) sum += pe1[(size_t)(b * NPT + lst[i]) * 512 + j];
      float t = sum * invc + b1s[j];
      hidm[(size_t)cell * 512 + j] = t / (1.f + expf(-t));
    }
  }
}

// ---------------------------------------------------------------------------
// K4: per-level GEMM with fused downsample + mask.
// out[img,k,y,x] = Mn(y,x) * ( g(y,x,:) @ w2[:,k] + Ss(y,x)*b2[k] )
template <int SCALE, int OFF, int AGG, int LOGW>
__global__ __launch_bounds__(256) void k_gemm(const float* __restrict__ hidm,
                                              const int* __restrict__ counts,
                                              const float* __restrict__ w2,
                                              const float* __restrict__ b2,
                                              float* __restrict__ out,
                                              int lvl, int ch) {
  const int WRES = 1 << LOGW;
  const int SDIM = WRES * WRES;
  __shared__ __align__(16) float As[64 * 128];
  __shared__ __align__(16) float Ws[64 * 128];
  __shared__ float Ss[64], Mn[64];
  int img = blockIdx.z;
  int k0 = blockIdx.y * 64;
  int s0 = blockIdx.x * 64;
  const int cbase = img * 1024;

  // stage W^T: Ws[k][m] = w2[m*ch + k0+k], XOR-swizzled on m-groups
  for (int idx = threadIdx.x; idx < 64 * MID; idx += 256) {
    int k = idx & 63, m = idx >> 6;
    Ws[k * 128 + (m ^ ((k & 7) << 2))] = w2[(size_t)m * ch + k0 + k];
  }
  // stage A (aggregated, masked)
  for (int idx = threadIdx.x; idx < 64 * MID; idx += 256) {
    int s = idx >> 7, m = idx & 127;
    int sp = s0 + s;
    int y = sp >> LOGW, x = sp & (WRES - 1);
    float g;
    if (AGG) {
      int ay = SCALE * y + OFF, ax = SCALE * x + OFF;
      int c00 = cbase + ay * 32 + ax;
      float v = 0.f;
      int cc;
      cc = counts[c00];      v += (cc > 0) ? hidm[(size_t)c00 * 512 + lvl * 128 + m] : 0.f;
      cc = counts[c00 + 1];  v += (cc > 0) ? hidm[(size_t)(c00 + 1) * 512 + lvl * 128 + m] : 0.f;
      cc = counts[c00 + 32]; v += (cc > 0) ? hidm[(size_t)(c00 + 32) * 512 + lvl * 128 + m] : 0.f;
      cc = counts[c00 + 33]; v += (cc > 0) ? hidm[(size_t)(c00 + 33) * 512 + lvl * 128 + m] : 0.f;
      g = 0.25f * v;
    } else {
      int cell = cbase + sp;
      g = (counts[cell] > 0) ? hidm[(size_t)cell * 512 + lvl * 128 + m] : 0.f;
    }
    As[s * 128 + (m ^ ((s & 7) << 2))] = g;
  }
  // per-spatial mask terms
  if (threadIdx.x < 64) {
    int s = threadIdx.x;
    int sp = s0 + s;
    int y = sp >> LOGW, x = sp & (WRES - 1);
    if (AGG) {
      int ay = SCALE * y + OFF, ax = SCALE * x + OFF;
      int c00 = cbase + ay * 32 + ax;
      float m00 = counts[c00] > 0 ? 1.f : 0.f;
      float m01 = counts[c00 + 1] > 0 ? 1.f : 0.f;
      float m10 = counts[c00 + 32] > 0 ? 1.f : 0.f;
      float m11 = counts[c00 + 33] > 0 ? 1.f : 0.f;
      Ss[s] = 0.25f * (m00 + m01 + m10 + m11);
      Mn[s] = counts[cbase + (SCALE * y) * 32 + SCALE * x] > 0 ? 1.f : 0.f;
    } else {
      float mv = counts[cbase + sp] > 0 ? 1.f : 0.f;
      Ss[s] = mv;
      Mn[s] = mv;
    }
  }
  __syncthreads();

  int ts = threadIdx.x & 15;  // spatial lane (s = ts + 16*i) -> coalesced stores
  int tk = threadIdx.x >> 4;  // channel lane (k = tk + 16*j)
  float acc[4][4] = {};       // [j: k][i: s]
  for (int mb = 0; mb < 32; ++mb) {
    int m4 = mb << 2;
    float4 a[4], w[4];
#pragma unroll
    for (int i = 0; i < 4; ++i) {
      int r = ts + 16 * i;
      a[i] = *reinterpret_cast<const float4*>(&As[r * 128 + (m4 ^ ((r & 7) << 2))]);
    }
#pragma unroll
    for (int j = 0; j < 4; ++j) {
      int r = tk + 16 * j;
      w[j] = *reinterpret_cast<const float4*>(&Ws[r * 128 + (m4 ^ ((r & 7) << 2))]);
    }
#pragma unroll
    for (int j = 0; j < 4; ++j) {
#pragma unroll
      for (int i = 0; i < 4; ++i) {
        float t = acc[j][i];
        t = fmaf(a[i].x, w[j].x, t);
        t = fmaf(a[i].y, w[j].y, t);
        t = fmaf(a[i].z, w[j].z, t);
        t = fmaf(a[i].w, w[j].w, t);
        acc[j][i] = t;
      }
    }
  }
  // epilogue
#pragma unroll
  for (int j = 0; j < 4; ++j) {
    int k = k0 + tk + 16 * j;
    float bv = b2[k];
    float* op = out + ((size_t)img * ch + k) * SDIM + s0;
#pragma unroll
    for (int i = 0; i < 4; ++i) {
      int s = ts + 16 * i;
      op[s] = Mn[s] * (acc[j][i] + Ss[s] * bv);
    }
  }
}

// ---------------------------------------------------------------------------
__global__ __launch_bounds__(256) void k_ones(float* __restrict__ p, int n) {
  int i = blockIdx.x * 256 + threadIdx.x;
  if (i < n) p[i] = 1.f;
}

// ---------------------------------------------------------------------------
extern "C" void kernel_launch(void* const* d_in, const int* in_sizes, int n_in,
                              void* d_out, int out_size, void* d_ws, size_t ws_size,
                              hipStream_t stream) {
  const float* pe = (const float*)d_in[0];
  const float* kp = (const float*)d_in[1];
  const int* subsets = (const int*)d_in[2];
  // d_in[3] = pose_latents (unused by the reference)
  const float* w1s = (const float*)d_in[4];
  const float* b1s = (const float*)d_in[5];
  const float* w2l[4] = {(const float*)d_in[6], (const float*)d_in[8],
                         (const float*)d_in[10], (const float*)d_in[12]};
  const float* b2l[4] = {(const float*)d_in[7], (const float*)d_in[9],
                         (const float*)d_in[11], (const float*)d_in[13]};
  float* out = (float*)d_out;

  // workspace layout (4-byte units)
  float* pe1 = (float*)d_ws;                   // 131072 floats
  int* counts = (int*)(pe1 + 131072);          // 32768 ints
  int* plist = counts + 32768;                 // 32768*32 ints
  int* wcnt = plist + 32768 * 32;              // 16 ints (aligned pad)
  int* wlist = wcnt + 16;                      // 32768 ints
  float* hidm = (float*)(wlist + 32768);       // 32768*512 floats
  float* part = hidm;                          // 16*131072 floats, consumed before hidm written

  hipMemsetAsync(wcnt, 0, sizeof(int), stream);

  k_pe1p<<<dim3(8, 4, 16), dim3(256), 0, stream>>>(pe, w1s, part);
  k_red<<<dim3(128), dim3(256), 0, stream>>>(part, pe1);
  k_bin<<<dim3(32), dim3(128), 0, stream>>>(kp, subsets, counts, plist, wcnt, wlist);
  k_hid<<<dim3(1024), dim3(256), 0, stream>>>(pe1, counts, plist, wcnt, wlist, b1s, hidm);

  float* out0 = out;                  // (2,16,320,32,32)  = 10485760
  float* out1 = out + 10485760;       // (2,16,640,16,16)  =  5242880
  float* out2 = out + 15728640;       // (2,16,1280,8,8)   =  2621440
  float* out3 = out + 18350080;       // (2,16,1280,8,8)   =  2621440
  float* lossm = out + 20971520;      // (2,16,4,32,32)    =   131072

  k_gemm<1, 0, 0, 5><<<dim3(16, 5, 32), dim3(256), 0, stream>>>(hidm, counts, w2l[0], b2l[0], out0, 0, 320);
  k_gemm<2, 0, 1, 4><<<dim3(4, 10, 32), dim3(256), 0, stream>>>(hidm, counts, w2l[1], b2l[1], out1, 1, 640);
  k_gemm<4, 1, 1, 3><<<dim3(1, 20, 32), dim3(256), 0, stream>>>(hidm, counts, w2l[2], b2l[2], out2, 2, 1280);
  k_gemm<4, 1, 1, 3><<<dim3(1, 20, 32), dim3(256), 0, stream>>>(hidm, counts, w2l[3], b2l[3], out3, 3, 1280);

  k_ones<<<dim3(512), dim3(256), 0, stream>>>(lossm, 131072);
}

// Round 3
// 93.995 us; speedup vs baseline: 4.5397x; 3.0307x over previous
//
#include <hip/hip_runtime.h>
#include <cstdint>
#include <cstddef>

// Problem constants
#define BB 2
#define FF 16
#define NPT 128
#define CC 1280
#define MID 128
// base grid 32x32 per (b,f) image; 32 images; 32768 cells; H-slice = 32768*128

typedef __attribute__((ext_vector_type(8))) short bf16x8;
typedef __attribute__((ext_vector_type(4))) float f32x4;

__device__ __forceinline__ unsigned short f2bf(float f) {
  unsigned u = __builtin_bit_cast(unsigned, f);
  u += 0x7FFFu + ((u >> 16) & 1u);  // RNE
  return (unsigned short)(u >> 16);
}
__device__ __forceinline__ float bf2f(unsigned short s) {
  return __builtin_bit_cast(float, (unsigned)s << 16);
}

// ---------------------------------------------------------------------------
// K1a: split-K partial GEMM  pe(256x1280) @ w1s(1280x512) -> part[z][256][512]
__global__ __launch_bounds__(256) void k_pe1p(const float* __restrict__ pe,
                                              const float* __restrict__ w1s,
                                              float* __restrict__ part) {
  const int KC = 80;
  __shared__ __align__(16) float As[64 * 84];
  __shared__ __align__(16) float Bs[KC * 64];
  int n0 = blockIdx.x * 64;
  int m0 = blockIdx.y * 64;
  int kc0 = blockIdx.z * KC;
  int tid = threadIdx.x;
  for (int idx = tid; idx < 64 * 20; idx += 256) {
    int row = idx / 20, kk = idx % 20;
    float4 v = *reinterpret_cast<const float4*>(&pe[(size_t)(m0 + row) * CC + kc0 + kk * 4]);
    *reinterpret_cast<float4*>(&As[row * 84 + kk * 4]) = v;
  }
  int l = n0 >> 7, m0c = n0 & 127;
  const float* wbase = w1s + (size_t)l * CC * MID + m0c;
  for (int idx = tid; idx < KC * 16; idx += 256) {
    int k = idx / 16, cg = idx % 16;
    float4 v = *reinterpret_cast<const float4*>(&wbase[(size_t)(kc0 + k) * MID + cg * 4]);
    *reinterpret_cast<float4*>(&Bs[k * 64 + cg * 4]) = v;
  }
  __syncthreads();
  int tx = tid & 15, ty = tid >> 4;
  float acc[4][4] = {};
  for (int k4 = 0; k4 < KC; k4 += 4) {
    float4 a[4], b[4];
#pragma unroll
    for (int i = 0; i < 4; ++i)
      a[i] = *reinterpret_cast<const float4*>(&As[(ty * 4 + i) * 84 + k4]);
#pragma unroll
    for (int kk = 0; kk < 4; ++kk)
      b[kk] = *reinterpret_cast<const float4*>(&Bs[(k4 + kk) * 64 + tx * 4]);
#pragma unroll
    for (int i = 0; i < 4; ++i) {
      float av[4] = {a[i].x, a[i].y, a[i].z, a[i].w};
#pragma unroll
      for (int kk = 0; kk < 4; ++kk) {
        acc[i][0] = fmaf(av[kk], b[kk].x, acc[i][0]);
        acc[i][1] = fmaf(av[kk], b[kk].y, acc[i][1]);
        acc[i][2] = fmaf(av[kk], b[kk].z, acc[i][2]);
        acc[i][3] = fmaf(av[kk], b[kk].w, acc[i][3]);
      }
    }
  }
  float* pb = part + (size_t)blockIdx.z * 131072;
#pragma unroll
  for (int i = 0; i < 4; ++i) {
    float4 v = make_float4(acc[i][0], acc[i][1], acc[i][2], acc[i][3]);
    *reinterpret_cast<float4*>(&pb[(size_t)(m0 + ty * 4 + i) * 512 + n0 + tx * 4]) = v;
  }
}

// K1b: pe1 = sum of 16 partials
__global__ __launch_bounds__(256) void k_red(const float* __restrict__ part,
                                             float* __restrict__ pe1) {
  int i = blockIdx.x * 256 + threadIdx.x;
  float4 s = make_float4(0.f, 0.f, 0.f, 0.f);
#pragma unroll
  for (int z = 0; z < 16; ++z) {
    float4 v = *reinterpret_cast<const float4*>(&part[(size_t)z * 131072 + (size_t)i * 4]);
    s.x += v.x; s.y += v.y; s.z += v.z; s.w += v.w;
  }
  *reinterpret_cast<float4*>(&pe1[(size_t)i * 4]) = s;
}

// ---------------------------------------------------------------------------
// K2: per-image counting sort of points into cells
__global__ __launch_bounds__(128) void k_bin(const float* __restrict__ kp,
                                             const int* __restrict__ subsets,
                                             int* __restrict__ counts,
                                             int* __restrict__ plist) {
  int bf = blockIdx.x;
  __shared__ int lcnt[1024];
  for (int i = threadIdx.x; i < 1024; i += 128) lcnt[i] = 0;
  __syncthreads();
  int n = threadIdx.x;
  int p = bf * NPT + n;
  float kx = kp[2 * p], ky = kp[2 * p + 1];
  int sub = subsets[p];
  if (fminf(kx, ky) >= 0.f && sub != -1) {
    int px = (int)floorf(kx * 32.f);
    px = px < 0 ? 0 : (px > 31 ? 31 : px);
    int py = (int)floorf(ky * 32.f);
    py = py < 0 ? 0 : (py > 31 ? 31 : py);
    int cell = py * 32 + px;
    int slot = atomicAdd(&lcnt[cell], 1);
    if (slot < 32) plist[((size_t)bf * 1024 + cell) * 32 + slot] = n;
  }
  __syncthreads();
  for (int i = threadIdx.x; i < 1024; i += 128) counts[bf * 1024 + i] = lcnt[i];
}

// ---------------------------------------------------------------------------
// K3: all cells. Non-empty: H[l][cell][m] = bf16(silu(mean + b1)). Empty: 0.
__global__ __launch_bounds__(256) void k_hid(const float* __restrict__ pe1,
                                             const int* __restrict__ counts,
                                             const int* __restrict__ plist,
                                             const float* __restrict__ b1s,
                                             unsigned short* __restrict__ H) {
  int cell = blockIdx.x;
  int c = counts[cell];
  int t = threadIdx.x;
  if (c == 0) {
    unsigned* dst = (unsigned*)(H + (size_t)(t >> 6) * 4194304 + (size_t)cell * 128);
    dst[t & 63] = 0u;
    return;
  }
  int cu = c < 32 ? c : 32;
  int b = cell >> 14;
  __shared__ int lst[32];
  if (t < cu) lst[t] = plist[(size_t)cell * 32 + t];
  __syncthreads();
  float invc = 1.f / (float)c;
  float s0 = 0.f, s1 = 0.f;
  for (int i = 0; i < cu; ++i) {
    const float* row = pe1 + (size_t)(b * NPT + lst[i]) * 512;
    s0 += row[t];
    s1 += row[t + 256];
  }
  float t0 = s0 * invc + b1s[t];
  float t1 = s1 * invc + b1s[t + 256];
  t0 = t0 / (1.f + expf(-t0));
  t1 = t1 / (1.f + expf(-t1));
  int l0 = t >> 7, m = t & 127;
  H[(size_t)l0 * 4194304 + (size_t)cell * 128 + m] = f2bf(t0);
  H[(size_t)(l0 + 2) * 4194304 + (size_t)cell * 128 + m] = f2bf(t1);
}

// ---------------------------------------------------------------------------
// K4: w2 [128][ch] f32 -> W2T [ch][128] bf16
__global__ __launch_bounds__(128) void k_w2t(const float* __restrict__ w2,
                                             unsigned short* __restrict__ wt, int ch) {
  int c = blockIdx.x;
  int m = threadIdx.x;
  wt[(size_t)c * 128 + m] = f2bf(w2[(size_t)m * ch + c]);
}

// ---------------------------------------------------------------------------
// K5: 2x2 aggregation for levels 1-3: A[row][128] bf16, Ss/Mn per row.
template <int SCALE, int OFF, int LOGW>
__global__ __launch_bounds__(256) void k_agg(const unsigned short* __restrict__ Hl,
                                             const int* __restrict__ counts,
                                             unsigned short* __restrict__ A,
                                             float* __restrict__ Ss,
                                             float* __restrict__ Mn) {
  const int W = 1 << LOGW;
  int m = threadIdx.x & 127;
  int row = blockIdx.x * 2 + (threadIdx.x >> 7);
  int img = row >> (2 * LOGW);
  int sp = row & (W * W - 1);
  int y = sp >> LOGW, x = sp & (W - 1);
  int c00 = img * 1024 + (SCALE * y + OFF) * 32 + (SCALE * x + OFF);
  float s = bf2f(Hl[(size_t)c00 * 128 + m]) + bf2f(Hl[(size_t)(c00 + 1) * 128 + m]) +
            bf2f(Hl[(size_t)(c00 + 32) * 128 + m]) + bf2f(Hl[(size_t)(c00 + 33) * 128 + m]);
  A[(size_t)row * 128 + m] = f2bf(0.25f * s);
  if (m == 0) {
    float sm = (counts[c00] > 0 ? 1.f : 0.f) + (counts[c00 + 1] > 0 ? 1.f : 0.f) +
               (counts[c00 + 32] > 0 ? 1.f : 0.f) + (counts[c00 + 33] > 0 ? 1.f : 0.f);
    Ss[row] = 0.25f * sm;
    Mn[row] = counts[img * 1024 + (SCALE * y) * 32 + SCALE * x] > 0 ? 1.f : 0.f;
  }
}

// ---------------------------------------------------------------------------
// K6: MFMA GEMM. out[img,ch,sp] = Mn(sp)*( A[sp,:]@W2T[ch,:] + Ss(sp)*b2[ch] )
// Block: 64 sp x 64 ch, 4 waves (2x2), 16x16x32 bf16 MFMA, swizzled LDS.
template <int LOGW, int CHT, bool USE_CNT>
__global__ __launch_bounds__(256) void k_mgemm(const unsigned short* __restrict__ A,
                                               const unsigned short* __restrict__ W2,
                                               const float* __restrict__ b2,
                                               const int* __restrict__ counts,
                                               const float* __restrict__ Ss,
                                               const float* __restrict__ Mn,
                                               float* __restrict__ out, int ch) {
  const int SDIM = 1 << (2 * LOGW);
  __shared__ __align__(16) unsigned short Asl[64 * 128];
  __shared__ __align__(16) unsigned short Wsl[64 * 128];
  int r0 = blockIdx.x * 64;
  int img = r0 >> (2 * LOGW);
  int tid = threadIdx.x;
  // stage A (granule-swizzled: granule g of row r lands at g^(r&7))
  for (int idx = tid; idx < 1024; idx += 256) {
    int r = idx >> 4, g = idx & 15;
    uint4 v = *reinterpret_cast<const uint4*>(A + (size_t)(r0 + r) * 128 + g * 8);
    *reinterpret_cast<uint4*>(&Asl[r * 128 + ((g ^ (r & 7)) << 3)]) = v;
  }
  int lane = tid & 63;
  int wave = tid >> 6;
  int lr = lane & 15, lk = lane >> 4;
  int choff = (wave & 1) * 32, spoff = (wave >> 1) * 32;

  for (int it = 0; it < CHT; ++it) {
    int k0 = (blockIdx.y * CHT + it) * 64;
    __syncthreads();
    for (int idx = tid; idx < 1024; idx += 256) {
      int r = idx >> 4, g = idx & 15;
      uint4 v = *reinterpret_cast<const uint4*>(W2 + (size_t)(k0 + r) * 128 + g * 8);
      *reinterpret_cast<uint4*>(&Wsl[r * 128 + ((g ^ (r & 7)) << 3)]) = v;
    }
    __syncthreads();
    f32x4 acc00 = {0.f, 0.f, 0.f, 0.f}, acc01 = acc00, acc10 = acc00, acc11 = acc00;
#pragma unroll
    for (int kk = 0; kk < 128; kk += 32) {
      int gbase = (kk >> 3) + lk;
      int r0w = choff + lr, r1w = choff + 16 + lr;
      int r0a = spoff + lr, r1a = spoff + 16 + lr;
      bf16x8 wf0 = *reinterpret_cast<const bf16x8*>(&Wsl[r0w * 128 + ((gbase ^ (r0w & 7)) << 3)]);
      bf16x8 wf1 = *reinterpret_cast<const bf16x8*>(&Wsl[r1w * 128 + ((gbase ^ (r1w & 7)) << 3)]);
      bf16x8 af0 = *reinterpret_cast<const bf16x8*>(&Asl[r0a * 128 + ((gbase ^ (r0a & 7)) << 3)]);
      bf16x8 af1 = *reinterpret_cast<const bf16x8*>(&Asl[r1a * 128 + ((gbase ^ (r1a & 7)) << 3)]);
      acc00 = __builtin_amdgcn_mfma_f32_16x16x32_bf16(wf0, af0, acc00, 0, 0, 0);
      acc01 = __builtin_amdgcn_mfma_f32_16x16x32_bf16(wf0, af1, acc01, 0, 0, 0);
      acc10 = __builtin_amdgcn_mfma_f32_16x16x32_bf16(wf1, af0, acc10, 0, 0, 0);
      acc11 = __builtin_amdgcn_mfma_f32_16x16x32_bf16(wf1, af1, acc11, 0, 0, 0);
    }
#define EPI(ACC, CI, SI)                                                          \
    {                                                                             \
      int spl = spoff + (SI) * 16 + lr;                                           \
      int absrow = r0 + spl;                                                      \
      float ss, mn;                                                               \
      if constexpr (USE_CNT) { mn = counts[absrow] > 0 ? 1.f : 0.f; ss = mn; }    \
      else { ss = Ss[absrow]; mn = Mn[absrow]; }                                  \
      float* op = out + (size_t)img * ch * SDIM + (absrow & (SDIM - 1));          \
      _Pragma("unroll")                                                           \
      for (int rr = 0; rr < 4; ++rr) {                                            \
        int chl = k0 + choff + (CI) * 16 + lk * 4 + rr;                           \
        op[(size_t)chl * SDIM] = mn * (ACC[rr] + ss * b2[chl]);                   \
      }                                                                           \
    }
    EPI(acc00, 0, 0)
    EPI(acc01, 0, 1)
    EPI(acc10, 1, 0)
    EPI(acc11, 1, 1)
#undef EPI
  }
}

// ---------------------------------------------------------------------------
__global__ __launch_bounds__(256) void k_ones(float* __restrict__ p, int n) {
  int i = blockIdx.x * 256 + threadIdx.x;
  if (i < n) p[i] = 1.f;
}

// ---------------------------------------------------------------------------
extern "C" void kernel_launch(void* const* d_in, const int* in_sizes, int n_in,
                              void* d_out, int out_size, void* d_ws, size_t ws_size,
                              hipStream_t stream) {
  const float* pe = (const float*)d_in[0];
  const float* kp = (const float*)d_in[1];
  const int* subsets = (const int*)d_in[2];
  const float* w1s = (const float*)d_in[4];
  const float* b1s = (const float*)d_in[5];
  const float* w2l[4] = {(const float*)d_in[6], (const float*)d_in[8],
                         (const float*)d_in[10], (const float*)d_in[12]};
  const float* b2l[4] = {(const float*)d_in[7], (const float*)d_in[9],
                         (const float*)d_in[11], (const float*)d_in[13]};
  float* out = (float*)d_out;

  // workspace layout
  float* pe1 = (float*)d_ws;                         // 131072 f32
  float* part = pe1 + 131072;                        // 16*131072 f32
  int* counts = (int*)(part + 2097152);              // 32768
  int* plist = counts + 32768;                       // 32768*32
  unsigned short* H = (unsigned short*)(plist + 1048576);  // 4*4194304 bf16
  unsigned short* A1 = H + 16777216;                 // 8192*128
  unsigned short* A2 = A1 + 1048576;                 // 2048*128
  unsigned short* A3 = A2 + 262144;                  // 2048*128
  unsigned short* W2T0 = A3 + 262144;                // 320*128
  unsigned short* W2T1 = W2T0 + 40960;               // 640*128
  unsigned short* W2T2 = W2T1 + 81920;               // 1280*128
  unsigned short* W2T3 = W2T2 + 163840;              // 1280*128
  float* Ss1 = (float*)(W2T3 + 163840);              // 8192
  float* Mn1 = Ss1 + 8192;
  float* Ss2 = Mn1 + 8192;                           // 2048
  float* Mn2 = Ss2 + 2048;
  float* Ss3 = Mn2 + 2048;
  float* Mn3 = Ss3 + 2048;

  k_w2t<<<dim3(320), dim3(128), 0, stream>>>(w2l[0], W2T0, 320);
  k_w2t<<<dim3(640), dim3(128), 0, stream>>>(w2l[1], W2T1, 640);
  k_w2t<<<dim3(1280), dim3(128), 0, stream>>>(w2l[2], W2T2, 1280);
  k_w2t<<<dim3(1280), dim3(128), 0, stream>>>(w2l[3], W2T3, 1280);

  k_pe1p<<<dim3(8, 4, 16), dim3(256), 0, stream>>>(pe, w1s, part);
  k_red<<<dim3(128), dim3(256), 0, stream>>>(part, pe1);
  k_bin<<<dim3(32), dim3(128), 0, stream>>>(kp, subsets, counts, plist);
  k_hid<<<dim3(32768), dim3(256), 0, stream>>>(pe1, counts, plist, b1s, H);

  k_agg<2, 0, 4><<<dim3(4096), dim3(256), 0, stream>>>(H + 1 * 4194304, counts, A1, Ss1, Mn1);
  k_agg<4, 1, 3><<<dim3(1024), dim3(256), 0, stream>>>(H + 2 * 4194304, counts, A2, Ss2, Mn2);
  k_agg<4, 1, 3><<<dim3(1024), dim3(256), 0, stream>>>(H + 3 * 4194304, counts, A3, Ss3, Mn3);

  float* out0 = out;                  // (2,16,320,32,32)
  float* out1 = out + 10485760;       // (2,16,640,16,16)
  float* out2 = out + 15728640;       // (2,16,1280,8,8)
  float* out3 = out + 18350080;       // (2,16,1280,8,8)
  float* lossm = out + 20971520;      // (2,16,4,32,32)

  k_mgemm<5, 5, true><<<dim3(512, 1), dim3(256), 0, stream>>>(H, W2T0, b2l[0], counts, nullptr, nullptr, out0, 320);
  k_mgemm<4, 1, false><<<dim3(128, 10), dim3(256), 0, stream>>>(A1, W2T1, b2l[1], nullptr, Ss1, Mn1, out1, 640);
  k_mgemm<3, 1, false><<<dim3(32, 20), dim3(256), 0, stream>>>(A2, W2T2, b2l[2], nullptr, Ss2, Mn2, out2, 1280);
  k_mgemm<3, 1, false><<<dim3(32, 20), dim3(256), 0, stream>>>(A3, W2T3, b2l[3], nullptr, Ss3, Mn3, out3, 1280);

  k_ones<<<dim3(512), dim3(256), 0, stream>>>(lossm, 131072);
}

// Round 4
// 58.069 us; speedup vs baseline: 7.3483x; 1.6187x over previous
//
#include <hip/hip_runtime.h>
#include <cstdint>
#include <cstddef>

#define BB 2
#define FF 16
#define NPT 128
#define CC 1280
#define MID 128

typedef __attribute__((ext_vector_type(8))) short bf16x8;
typedef __attribute__((ext_vector_type(4))) float f32x4;

__device__ __forceinline__ unsigned short f2bf(float f) {
  unsigned u = __builtin_bit_cast(unsigned, f);
  u += 0x7FFFu + ((u >> 16) & 1u);  // RNE
  return (unsigned short)(u >> 16);
}
__device__ __forceinline__ float bf2f(unsigned short s) {
  return __builtin_bit_cast(float, (unsigned)s << 16);
}

// ---------------------------------------------------------------------------
// K0 "pre": fused  (a) w2 transpose f32->bf16 [ch][128], coalesced via LDS
//                  (b) per-image point binning (counts + plist)
//                  (c) loss-mask ones fill
__global__ __launch_bounds__(256) void k_pre(const float* __restrict__ w2_0,
                                             const float* __restrict__ w2_1,
                                             const float* __restrict__ w2_2,
                                             const float* __restrict__ w2_3,
                                             unsigned short* __restrict__ W2T0,
                                             unsigned short* __restrict__ W2T1,
                                             unsigned short* __restrict__ W2T2,
                                             unsigned short* __restrict__ W2T3,
                                             const float* __restrict__ kp,
                                             const int* __restrict__ subsets,
                                             int* __restrict__ counts,
                                             int* __restrict__ plist,
                                             float* __restrict__ lossm) {
  __shared__ float ts[32][33];  // 4224B; also aliased as 1024 ints for binning
  int b = blockIdx.x;
  int tid = threadIdx.x;
  if (b < 440) {
    // ---- transpose segment: levels {40,80,160,160} blocks of 32m x 32c tiles
    const float* w2;
    unsigned short* wt;
    int ch, local;
    if (b < 40) { w2 = w2_0; wt = W2T0; ch = 320; local = b; }
    else if (b < 120) { w2 = w2_1; wt = W2T1; ch = 640; local = b - 40; }
    else if (b < 280) { w2 = w2_2; wt = W2T2; ch = 1280; local = b - 120; }
    else { w2 = w2_3; wt = W2T3; ch = 1280; local = b - 280; }
    int ctiles = ch >> 5;
    int mt = local / ctiles, ct = local % ctiles;
    int m0 = mt * 32, c0 = ct * 32;
    int i = tid >> 5, j = tid & 31;
#pragma unroll
    for (int r = 0; r < 4; ++r) {
      int m = r * 8 + i;
      ts[m][j] = w2[(size_t)(m0 + m) * ch + c0 + j];
    }
    __syncthreads();
#pragma unroll
    for (int r = 0; r < 4; ++r) {
      int c = r * 8 + i;
      wt[(size_t)(c0 + c) * 128 + m0 + j] = f2bf(ts[j][c]);
    }
  } else if (b < 472) {
    // ---- binning segment: one block per image
    int bf = b - 440;
    int* lcnt = (int*)&ts[0][0];
    for (int i = tid; i < 1024; i += 256) lcnt[i] = 0;
    __syncthreads();
    if (tid < NPT) {
      int p = bf * NPT + tid;
      float kx = kp[2 * p], ky = kp[2 * p + 1];
      int sub = subsets[p];
      if (fminf(kx, ky) >= 0.f && sub != -1) {
        int px = (int)floorf(kx * 32.f);
        px = px < 0 ? 0 : (px > 31 ? 31 : px);
        int py = (int)floorf(ky * 32.f);
        py = py < 0 ? 0 : (py > 31 ? 31 : py);
        int cell = py * 32 + px;
        int slot = atomicAdd(&lcnt[cell], 1);
        if (slot < 32) plist[((size_t)bf * 1024 + cell) * 32 + slot] = tid;
      }
    }
    __syncthreads();
    for (int i = tid; i < 1024; i += 256) counts[bf * 1024 + i] = lcnt[i];
  } else {
    // ---- ones segment: 128 blocks x 256 threads x float4 = 131072 floats
    int idx = (b - 472) * 256 + tid;
    *reinterpret_cast<float4*>(lossm + (size_t)idx * 4) = make_float4(1.f, 1.f, 1.f, 1.f);
  }
}

// ---------------------------------------------------------------------------
// K1a: split-K partial GEMM  pe(256x1280) @ w1s(1280x512) -> part[z][256][512]
__global__ __launch_bounds__(256) void k_pe1p(const float* __restrict__ pe,
                                              const float* __restrict__ w1s,
                                              float* __restrict__ part) {
  const int KC = 80;
  __shared__ __align__(16) float As[64 * 84];
  __shared__ __align__(16) float Bs[KC * 64];
  int n0 = blockIdx.x * 64;
  int m0 = blockIdx.y * 64;
  int kc0 = blockIdx.z * KC;
  int tid = threadIdx.x;
  for (int idx = tid; idx < 64 * 20; idx += 256) {
    int row = idx / 20, kk = idx % 20;
    float4 v = *reinterpret_cast<const float4*>(&pe[(size_t)(m0 + row) * CC + kc0 + kk * 4]);
    *reinterpret_cast<float4*>(&As[row * 84 + kk * 4]) = v;
  }
  int l = n0 >> 7, m0c = n0 & 127;
  const float* wbase = w1s + (size_t)l * CC * MID + m0c;
  for (int idx = tid; idx < KC * 16; idx += 256) {
    int k = idx / 16, cg = idx % 16;
    float4 v = *reinterpret_cast<const float4*>(&wbase[(size_t)(kc0 + k) * MID + cg * 4]);
    *reinterpret_cast<float4*>(&Bs[k * 64 + cg * 4]) = v;
  }
  __syncthreads();
  int tx = tid & 15, ty = tid >> 4;
  float acc[4][4] = {};
  for (int k4 = 0; k4 < KC; k4 += 4) {
    float4 a[4], bb[4];
#pragma unroll
    for (int i = 0; i < 4; ++i)
      a[i] = *reinterpret_cast<const float4*>(&As[(ty * 4 + i) * 84 + k4]);
#pragma unroll
    for (int kk = 0; kk < 4; ++kk)
      bb[kk] = *reinterpret_cast<const float4*>(&Bs[(k4 + kk) * 64 + tx * 4]);
#pragma unroll
    for (int i = 0; i < 4; ++i) {
      float av[4] = {a[i].x, a[i].y, a[i].z, a[i].w};
#pragma unroll
      for (int kk = 0; kk < 4; ++kk) {
        acc[i][0] = fmaf(av[kk], bb[kk].x, acc[i][0]);
        acc[i][1] = fmaf(av[kk], bb[kk].y, acc[i][1]);
        acc[i][2] = fmaf(av[kk], bb[kk].z, acc[i][2]);
        acc[i][3] = fmaf(av[kk], bb[kk].w, acc[i][3]);
      }
    }
  }
  float* pb = part + (size_t)blockIdx.z * 131072;
#pragma unroll
  for (int i = 0; i < 4; ++i) {
    float4 v = make_float4(acc[i][0], acc[i][1], acc[i][2], acc[i][3]);
    *reinterpret_cast<float4*>(&pb[(size_t)(m0 + ty * 4 + i) * 512 + n0 + tx * 4]) = v;
  }
}

// K1b: pe1 = sum of 16 partials
__global__ __launch_bounds__(256) void k_red(const float* __restrict__ part,
                                             float* __restrict__ pe1) {
  int i = blockIdx.x * 256 + threadIdx.x;
  float4 s = make_float4(0.f, 0.f, 0.f, 0.f);
#pragma unroll
  for (int z = 0; z < 16; ++z) {
    float4 v = *reinterpret_cast<const float4*>(&part[(size_t)z * 131072 + (size_t)i * 4]);
    s.x += v.x; s.y += v.y; s.z += v.z; s.w += v.w;
  }
  *reinterpret_cast<float4*>(&pe1[(size_t)i * 4]) = s;
}

// ---------------------------------------------------------------------------
// K2: non-empty cells only: H[l][cell][m] = bf16(silu(mean + b1)).
// 8 cells per block; empty cells skipped entirely (H left stale, never read).
__global__ __launch_bounds__(256) void k_hid2(const float* __restrict__ pe1,
                                              const int* __restrict__ counts,
                                              const int* __restrict__ plist,
                                              const float* __restrict__ b1s,
                                              unsigned short* __restrict__ H) {
  __shared__ int lst[32];
  int t = threadIdx.x;
  for (int q = 0; q < 8; ++q) {
    int cell = blockIdx.x * 8 + q;
    int c = counts[cell];
    if (c == 0) continue;  // block-uniform
    __syncthreads();
    int cu = c < 32 ? c : 32;
    if (t < cu) lst[t] = plist[(size_t)cell * 32 + t];
    __syncthreads();
    int b = cell >> 14;
    float invc = 1.f / (float)c;
    float s0 = 0.f, s1 = 0.f;
    for (int i = 0; i < cu; ++i) {
      const float* row = pe1 + (size_t)(b * NPT + lst[i]) * 512;
      s0 += row[t];
      s1 += row[t + 256];
    }
    float t0 = s0 * invc + b1s[t];
    float t1 = s1 * invc + b1s[t + 256];
    t0 = t0 / (1.f + expf(-t0));
    t1 = t1 / (1.f + expf(-t1));
    int l0 = t >> 7, m = t & 127;
    H[(size_t)l0 * 4194304 + (size_t)cell * 128 + m] = f2bf(t0);
    H[(size_t)(l0 + 2) * 4194304 + (size_t)cell * 128 + m] = f2bf(t1);
  }
}

// ---------------------------------------------------------------------------
// K3: merged 2x2 aggregation for levels 1-3, count-gated H reads.
template <int SCALE, int OFF, int LOGW>
__device__ __forceinline__ void agg_body(const unsigned short* __restrict__ Hl,
                                         const int* __restrict__ counts,
                                         unsigned short* __restrict__ A,
                                         float* __restrict__ Ss,
                                         float* __restrict__ Mn,
                                         int row, int m) {
  const int W = 1 << LOGW;
  int img = row >> (2 * LOGW);
  int sp = row & (W * W - 1);
  int y = sp >> LOGW, x = sp & (W - 1);
  int c00 = img * 1024 + (SCALE * y + OFF) * 32 + (SCALE * x + OFF);
  int n00 = counts[c00], n01 = counts[c00 + 1], n10 = counts[c00 + 32], n11 = counts[c00 + 33];
  float s = 0.f;
  if (n00 > 0) s += bf2f(Hl[(size_t)c00 * 128 + m]);
  if (n01 > 0) s += bf2f(Hl[(size_t)(c00 + 1) * 128 + m]);
  if (n10 > 0) s += bf2f(Hl[(size_t)(c00 + 32) * 128 + m]);
  if (n11 > 0) s += bf2f(Hl[(size_t)(c00 + 33) * 128 + m]);
  A[(size_t)row * 128 + m] = f2bf(0.25f * s);
  if (m == 0) {
    float sm = (n00 > 0 ? 1.f : 0.f) + (n01 > 0 ? 1.f : 0.f) +
               (n10 > 0 ? 1.f : 0.f) + (n11 > 0 ? 1.f : 0.f);
    Ss[row] = 0.25f * sm;
    Mn[row] = counts[img * 1024 + (SCALE * y) * 32 + SCALE * x] > 0 ? 1.f : 0.f;
  }
}

__global__ __launch_bounds__(256) void k_agg2(const unsigned short* __restrict__ H,
                                              const int* __restrict__ counts,
                                              unsigned short* __restrict__ A1,
                                              unsigned short* __restrict__ A2,
                                              unsigned short* __restrict__ A3,
                                              float* __restrict__ Ss1, float* __restrict__ Mn1,
                                              float* __restrict__ Ss2, float* __restrict__ Mn2,
                                              float* __restrict__ Ss3, float* __restrict__ Mn3) {
  int b = blockIdx.x;
  int m = threadIdx.x & 127;
  int half = threadIdx.x >> 7;
  if (b < 4096)
    agg_body<2, 0, 4>(H + 1 * 4194304, counts, A1, Ss1, Mn1, b * 2 + half, m);
  else if (b < 5120)
    agg_body<4, 1, 3>(H + 2 * 4194304, counts, A2, Ss2, Mn2, (b - 4096) * 2 + half, m);
  else
    agg_body<4, 1, 3>(H + 3 * 4194304, counts, A3, Ss3, Mn3, (b - 5120) * 2 + half, m);
}

// ---------------------------------------------------------------------------
// K4: merged MFMA GEMM, all 4 levels via block-segment decode.
template <int LOGW, int CHT, bool GATED>
__device__ __forceinline__ void mgemm_body(int bx, int by,
                                           const unsigned short* __restrict__ A,
                                           const unsigned short* __restrict__ W2,
                                           const float* __restrict__ b2,
                                           const int* __restrict__ counts,
                                           const float* __restrict__ Ss,
                                           const float* __restrict__ Mn,
                                           float* __restrict__ out, int ch,
                                           unsigned short* Asl, unsigned short* Wsl) {
  const int SDIM = 1 << (2 * LOGW);
  int r0 = bx * 64;
  int img = r0 >> (2 * LOGW);
  int tid = threadIdx.x;
  // stage A (granule-swizzled); level 0 gates on counts (H sparse-written)
  for (int idx = tid; idx < 1024; idx += 256) {
    int r = idx >> 4, g = idx & 15;
    uint4 v;
    if (GATED) {
      if (counts[r0 + r] > 0)
        v = *reinterpret_cast<const uint4*>(A + (size_t)(r0 + r) * 128 + g * 8);
      else
        v = make_uint4(0u, 0u, 0u, 0u);
    } else {
      v = *reinterpret_cast<const uint4*>(A + (size_t)(r0 + r) * 128 + g * 8);
    }
    *reinterpret_cast<uint4*>(&Asl[r * 128 + ((g ^ (r & 7)) << 3)]) = v;
  }
  int lane = tid & 63;
  int wave = tid >> 6;
  int lr = lane & 15, lk = lane >> 4;
  int choff = (wave & 1) * 32, spoff = (wave >> 1) * 32;

  for (int it = 0; it < CHT; ++it) {
    int k0 = (by * CHT + it) * 64;
    __syncthreads();
    for (int idx = tid; idx < 1024; idx += 256) {
      int r = idx >> 4, g = idx & 15;
      uint4 v = *reinterpret_cast<const uint4*>(W2 + (size_t)(k0 + r) * 128 + g * 8);
      *reinterpret_cast<uint4*>(&Wsl[r * 128 + ((g ^ (r & 7)) << 3)]) = v;
    }
    __syncthreads();
    f32x4 acc00 = {0.f, 0.f, 0.f, 0.f}, acc01 = acc00, acc10 = acc00, acc11 = acc00;
#pragma unroll
    for (int kk = 0; kk < 128; kk += 32) {
      int gbase = (kk >> 3) + lk;
      int r0w = choff + lr, r1w = choff + 16 + lr;
      int r0a = spoff + lr, r1a = spoff + 16 + lr;
      bf16x8 wf0 = *reinterpret_cast<const bf16x8*>(&Wsl[r0w * 128 + ((gbase ^ (r0w & 7)) << 3)]);
      bf16x8 wf1 = *reinterpret_cast<const bf16x8*>(&Wsl[r1w * 128 + ((gbase ^ (r1w & 7)) << 3)]);
      bf16x8 af0 = *reinterpret_cast<const bf16x8*>(&Asl[r0a * 128 + ((gbase ^ (r0a & 7)) << 3)]);
      bf16x8 af1 = *reinterpret_cast<const bf16x8*>(&Asl[r1a * 128 + ((gbase ^ (r1a & 7)) << 3)]);
      acc00 = __builtin_amdgcn_mfma_f32_16x16x32_bf16(wf0, af0, acc00, 0, 0, 0);
      acc01 = __builtin_amdgcn_mfma_f32_16x16x32_bf16(wf0, af1, acc01, 0, 0, 0);
      acc10 = __builtin_amdgcn_mfma_f32_16x16x32_bf16(wf1, af0, acc10, 0, 0, 0);
      acc11 = __builtin_amdgcn_mfma_f32_16x16x32_bf16(wf1, af1, acc11, 0, 0, 0);
    }
#define EPI(ACC, CI, SI)                                                          \
    {                                                                             \
      int spl = spoff + (SI) * 16 + lr;                                           \
      int absrow = r0 + spl;                                                      \
      float ss, mn;                                                               \
      if constexpr (GATED) { mn = counts[absrow] > 0 ? 1.f : 0.f; ss = mn; }      \
      else { ss = Ss[absrow]; mn = Mn[absrow]; }                                  \
      float* op = out + (size_t)img * ch * SDIM + (absrow & (SDIM - 1));          \
      _Pragma("unroll")                                                           \
      for (int rr = 0; rr < 4; ++rr) {                                            \
        int chl = k0 + choff + (CI) * 16 + lk * 4 + rr;                           \
        op[(size_t)chl * SDIM] = mn * (ACC[rr] + ss * b2[chl]);                   \
      }                                                                           \
    }
    EPI(acc00, 0, 0)
    EPI(acc01, 0, 1)
    EPI(acc10, 1, 0)
    EPI(acc11, 1, 1)
#undef EPI
  }
}

__global__ __launch_bounds__(256) void k_mgemm_all(
    const unsigned short* __restrict__ H,
    const unsigned short* __restrict__ A1, const unsigned short* __restrict__ A2,
    const unsigned short* __restrict__ A3,
    const unsigned short* __restrict__ W2T0, const unsigned short* __restrict__ W2T1,
    const unsigned short* __restrict__ W2T2, const unsigned short* __restrict__ W2T3,
    const float* __restrict__ b20, const float* __restrict__ b21,
    const float* __restrict__ b22, const float* __restrict__ b23,
    const int* __restrict__ counts,
    const float* __restrict__ Ss1, const float* __restrict__ Mn1,
    const float* __restrict__ Ss2, const float* __restrict__ Mn2,
    const float* __restrict__ Ss3, const float* __restrict__ Mn3,
    float* __restrict__ out0, float* __restrict__ out1,
    float* __restrict__ out2, float* __restrict__ out3) {
  __shared__ __align__(16) unsigned short Asl[64 * 128];
  __shared__ __align__(16) unsigned short Wsl[64 * 128];
  int b = blockIdx.x;
  if (b < 512) {
    mgemm_body<5, 5, true>(b, 0, H, W2T0, b20, counts, nullptr, nullptr, out0, 320, Asl, Wsl);
  } else if (b < 1792) {
    int l = b - 512;
    mgemm_body<4, 1, false>(l & 127, l >> 7, A1, W2T1, b21, nullptr, Ss1, Mn1, out1, 640, Asl, Wsl);
  } else if (b < 2432) {
    int l = b - 1792;
    mgemm_body<3, 1, false>(l & 31, l >> 5, A2, W2T2, b22, nullptr, Ss2, Mn2, out2, 1280, Asl, Wsl);
  } else {
    int l = b - 2432;
    mgemm_body<3, 1, false>(l & 31, l >> 5, A3, W2T3, b23, nullptr, Ss3, Mn3, out3, 1280, Asl, Wsl);
  }
}

// ---------------------------------------------------------------------------
extern "C" void kernel_launch(void* const* d_in, const int* in_sizes, int n_in,
                              void* d_out, int out_size, void* d_ws, size_t ws_size,
                              hipStream_t stream) {
  const float* pe = (const float*)d_in[0];
  const float* kp = (const float*)d_in[1];
  const int* subsets = (const int*)d_in[2];
  const float* w1s = (const float*)d_in[4];
  const float* b1s = (const float*)d_in[5];
  const float* w2l[4] = {(const float*)d_in[6], (const float*)d_in[8],
                         (const float*)d_in[10], (const float*)d_in[12]};
  const float* b2l[4] = {(const float*)d_in[7], (const float*)d_in[9],
                         (const float*)d_in[11], (const float*)d_in[13]};
  float* out = (float*)d_out;

  // workspace layout
  float* pe1 = (float*)d_ws;                         // 131072 f32
  float* part = pe1 + 131072;                        // 16*131072 f32
  int* counts = (int*)(part + 2097152);              // 32768
  int* plist = counts + 32768;                       // 32768*32
  unsigned short* H = (unsigned short*)(plist + 1048576);  // 4*4194304 bf16
  unsigned short* A1 = H + 16777216;                 // 8192*128
  unsigned short* A2 = A1 + 1048576;                 // 2048*128
  unsigned short* A3 = A2 + 262144;                  // 2048*128
  unsigned short* W2T0 = A3 + 262144;                // 320*128
  unsigned short* W2T1 = W2T0 + 40960;               // 640*128
  unsigned short* W2T2 = W2T1 + 81920;               // 1280*128
  unsigned short* W2T3 = W2T2 + 163840;              // 1280*128
  float* Ss1 = (float*)(W2T3 + 163840);              // 8192
  float* Mn1 = Ss1 + 8192;
  float* Ss2 = Mn1 + 8192;                           // 2048
  float* Mn2 = Ss2 + 2048;
  float* Ss3 = Mn2 + 2048;
  float* Mn3 = Ss3 + 2048;

  float* out0 = out;                  // (2,16,320,32,32)
  float* out1 = out + 10485760;       // (2,16,640,16,16)
  float* out2 = out + 15728640;       // (2,16,1280,8,8)
  float* out3 = out + 18350080;       // (2,16,1280,8,8)
  float* lossm = out + 20971520;      // (2,16,4,32,32)

  k_pre<<<dim3(600), dim3(256), 0, stream>>>(w2l[0], w2l[1], w2l[2], w2l[3],
                                             W2T0, W2T1, W2T2, W2T3,
                                             kp, subsets, counts, plist, lossm);
  k_pe1p<<<dim3(8, 4, 16), dim3(256), 0, stream>>>(pe, w1s, part);
  k_red<<<dim3(128), dim3(256), 0, stream>>>(part, pe1);
  k_hid2<<<dim3(4096), dim3(256), 0, stream>>>(pe1, counts, plist, b1s, H);
  k_agg2<<<dim3(6144), dim3(256), 0, stream>>>(H, counts, A1, A2, A3,
                                               Ss1, Mn1, Ss2, Mn2, Ss3, Mn3);
  k_mgemm_all<<<dim3(3072), dim3(256), 0, stream>>>(H, A1, A2, A3,
                                                    W2T0, W2T1, W2T2, W2T3,
                                                    b2l[0], b2l[1], b2l[2], b2l[3],
                                                    counts, Ss1, Mn1, Ss2, Mn2, Ss3, Mn3,
                                                    out0, out1, out2, out3);
}